// Round 12
// baseline (535.193 us; speedup 1.0000x reference)
//
#include <hip/hip_runtime.h>
#include <hip/hip_fp16.h>

// UniversalGRU: 2-layer GRU (B=2048, T=512, D=1, H=64) + FC(64->1).
// R12: ROWS=4 retry, de-confounded. 512 blocks x 512 thr = 2 blocks/CU
// (4 waves/SIMD, uncorrelated barriers between co-resident blocks).
// vs R5 (which regressed): stride-76 conflict-free hbuf (R11-proven),
// f16x2-packed 2-shfl-per-gate redistribution (R7-proven), ONE real
// gate-triple per lane. Layer-skewed lockstep: waves 0-3 = L0 step t,
// waves 4-7 = L1 step t-1, one barrier/t. M=16 MFMA tile, rows 0-3 real.

#define T_LEN 512
#define ROWS  4
#define XPAD  513
#define STR   76          // hbuf row stride in shorts (conflict-free, R11)

typedef float          f32x4 __attribute__((ext_vector_type(4)));
typedef __bf16         bf16x8 __attribute__((ext_vector_type(8)));
typedef unsigned short us8   __attribute__((ext_vector_type(8)));
typedef unsigned short ushort_t;

__device__ __forceinline__ float bf2f(ushort_t b){
    unsigned int u = ((unsigned int)b) << 16;
    return __uint_as_float(u);
}
__device__ __forceinline__ ushort_t f2bf(float f){
    unsigned int u = __float_as_uint(f);
    u = (u + 0x7FFFu + ((u >> 16) & 1u)) >> 16;   // RNE
    return (ushort_t)u;
}
__device__ __forceinline__ float ld_any(const void* p, int i, bool f32){
    return f32 ? ((const float*)p)[i] : bf2f(((const ushort_t*)p)[i]);
}
__device__ __forceinline__ float sigm(float x){
    float e = __expf(-x);
    return __fdividef(1.0f, 1.0f + e);
}
__device__ __forceinline__ float tanh_f(float x){
    float e = __expf(2.0f * x);
    return fmaf(-2.0f, __fdividef(1.0f, e + 1.0f), 1.0f);
}
__device__ __forceinline__ f32x4 mfma16(bf16x8 a, bf16x8 b, f32x4 c){
    return __builtin_amdgcn_mfma_f32_16x16x32_bf16(a, b, c, 0, 0, 0);
}
__device__ __forceinline__ float pack2(float a, float b){
    __half2 h = __floats2half2_rn(a, b);          // v_cvt_pkrtz
    return __builtin_bit_cast(float, h);
}
__device__ __forceinline__ float2 unpack2(float p){
    __half2 h = __builtin_bit_cast(__half2, p);
    return __half22float2(h);
}
// ROWS=4 redistribution: real C-rows 0-3 live in q=0 lanes' regs 0-3.
// Lane L=q*16+c takes reg q from lane c: 2 packed shfls + selects.
__device__ __forceinline__ float redist4(f32x4 v, int srcc, int q){
    float w01 = pack2(v[0], v[1]);
    float w23 = pack2(v[2], v[3]);
    float s01 = __shfl(w01, srcc);
    float s23 = __shfl(w23, srcc);
    float sel = (q & 2) ? s23 : s01;
    float2 uv = unpack2(sel);
    return (q & 1) ? uv.y : uv.x;
}
// Build a B-fragment (8 contiguous k's of W[n][k]) from either dtype.
__device__ __forceinline__ bf16x8 mk_frag(const void* W, int n, int kb, bool f32){
    us8 tmp;
    #pragma unroll
    for (int j = 0; j < 8; ++j){
        tmp[j] = f32 ? f2bf(((const float*)W)[n * 64 + kb + j])
                     : ((const ushort_t*)W)[n * 64 + kb + j];
    }
    return __builtin_bit_cast(bf16x8, tmp);
}

__global__ __launch_bounds__(512, 4) void gru_fused(
    const void* __restrict__ xv,
    const void* __restrict__ Wih0, const void* __restrict__ Whh0,
    const void* __restrict__ bih0, const void* __restrict__ bhh0,
    const void* __restrict__ Wih1, const void* __restrict__ Whh1,
    const void* __restrict__ bih1, const void* __restrict__ bhh1,
    const void* __restrict__ Wfc,  const void* __restrict__ bfc,
    void* __restrict__ outv)
{
    __shared__ float    xbuf[ROWS * XPAD];       // staged x (f32)
    __shared__ ushort_t hbufA[2][16 * STR];      // hA, A-layout bf16, dbuf
    __shared__ ushort_t hbufB[2][16 * STR];      // hB
    __shared__ float    outb[ROWS][68];

    const int tid  = threadIdx.x;
    const int wv   = tid >> 6;                   // 0..7
    const bool isL1 = (wv >= 4);
    const int w    = wv & 3;                     // n-tile group within role
    const int c    = tid & 15;                   // MFMA col-within-tile
    const int q    = (tid >> 4) & 3;             // quad; lane owns batch row q
    const int ih   = w * 16 + c;                 // owned h-col
    const long row0 = (long)blockIdx.x * ROWS;

    // dtype detection (uniform): fp32 misread as bf16 -> mantissa-noise
    // exponents in even ushort slots; true bf16 never exceeds exp 150.
    bool f32 = false;
    {
        const ushort_t* xs = (const ushort_t*)xv;
        for (int j = 0; j < 64; ++j){
            int e = (xs[2 * j] >> 7) & 0xFF;
            if (e > 150) f32 = true;
        }
    }

    // zero h double-buffers (rows 4-15 stay zero forever)
    {
        ushort_t* pa = &hbufA[0][0];
        ushort_t* pb = &hbufB[0][0];
        for (int k = tid; k < 2 * 16 * STR; k += 512){ pa[k] = 0; pb[k] = 0; }
    }
    // stage x: waves 0-3 load row wv (4 rows x 512), coalesced
    if (wv < 4){
        const int r = wv;
        const int g = tid & 63;
        if (f32){
            const f32x4* src = (const f32x4*)((const float*)xv + (row0 + r) * T_LEN);
            #pragma unroll
            for (int it = 0; it < 2; ++it){
                f32x4 v = src[g + 64 * it];
                #pragma unroll
                for (int j = 0; j < 4; ++j)
                    xbuf[r * XPAD + (g + 64 * it) * 4 + j] = v[j];
            }
        } else {
            const us8* src = (const us8*)((const ushort_t*)xv + (row0 + r) * T_LEN);
            us8 v = src[g];
            #pragma unroll
            for (int j = 0; j < 8; ++j)
                xbuf[r * XPAD + g * 8 + j] = bf2f(v[j]);
        }
    }

    // Role-specific weights. B[k][n]=W[n][k]; lane: n = 64*g + ih, k = 32*f+8*q+j.
    bf16x8 wA[3][2], wB[3][2];                   // L0: wA=Whh0. L1: wA=Wih1, wB=Whh1.
    float sxr = 0.f, sxz = 0.f, sxn = 0.f;
    float br, bz, bnx, bnh;
    if (!isL1){
        #pragma unroll
        for (int g = 0; g < 3; ++g){
            const int n = g * 64 + ih;
            #pragma unroll
            for (int f = 0; f < 2; ++f)
                wA[g][f] = mk_frag(Whh0, n, f * 32 + q * 8, f32);
        }
        sxr = ld_any(Wih0, ih, f32);
        sxz = ld_any(Wih0, 64 + ih, f32);
        sxn = ld_any(Wih0, 128 + ih, f32);
        br  = ld_any(bih0, ih, f32)       + ld_any(bhh0, ih, f32);
        bz  = ld_any(bih0, 64 + ih, f32)  + ld_any(bhh0, 64 + ih, f32);
        bnx = ld_any(bih0, 128 + ih, f32);
        bnh = ld_any(bhh0, 128 + ih, f32);
    } else {
        #pragma unroll
        for (int g = 0; g < 3; ++g){
            const int n = g * 64 + ih;
            #pragma unroll
            for (int f = 0; f < 2; ++f){
                wA[g][f] = mk_frag(Wih1, n, f * 32 + q * 8, f32);
                wB[g][f] = mk_frag(Whh1, n, f * 32 + q * 8, f32);
            }
        }
        br  = ld_any(bih1, ih, f32)       + ld_any(bhh1, ih, f32);
        bz  = ld_any(bih1, 64 + ih, f32)  + ld_any(bhh1, 64 + ih, f32);
        bnx = ld_any(bih1, 128 + ih, f32);
        bnh = ld_any(bhh1, 128 + ih, f32);
    }

    float hreg = 0.f;                  // fp32-carried h for (row q, col ih)
    const int aoff = c * STR + q * 8;  // A-frag base: A[m=c][k=8q(+32f)]

    __syncthreads();

    #pragma unroll 2
    for (int t = 0; t < T_LEN; ++t){
        const int p = t & 1;
        if (!isL1){
            // ---- layer 0, step t: hA(t) = GRU0(x(t), hA(t-1))
            us8 a0u = *(const us8*)&hbufA[p][aoff];
            us8 a1u = *(const us8*)&hbufA[p][aoff + 32];
            bf16x8 a0 = __builtin_bit_cast(bf16x8, a0u);
            bf16x8 a1 = __builtin_bit_cast(bf16x8, a1u);
            f32x4 aR = {br, br, br, br};
            f32x4 aZ = {bz, bz, bz, bz};
            f32x4 aN = {bnh, bnh, bnh, bnh};
            aR = mfma16(a0, wA[0][0], aR); aR = mfma16(a1, wA[0][1], aR);
            aZ = mfma16(a0, wA[1][0], aZ); aZ = mfma16(a1, wA[1][1], aZ);
            aN = mfma16(a0, wA[2][0], aN); aN = mfma16(a1, wA[2][1], aN);
            float gR = redist4(aR, c, q);
            float gZ = redist4(aZ, c, q);
            float gN = redist4(aN, c, q);
            float xm = xbuf[q * XPAD + t];
            float rg = sigm(fmaf(xm, sxr, gR));
            float zg = sigm(fmaf(xm, sxz, gZ));
            float ng = tanh_f(fmaf(xm, sxn, bnx) + rg * gN);
            hreg = ng + zg * (hreg - ng);
            hbufA[p ^ 1][q * STR + ih] = f2bf(hreg);
        } else if (t > 0){
            // ---- layer 1, step t-1: hB(t-1) = GRU1(hA(t-1), hB(t-2))
            us8 a0u = *(const us8*)&hbufA[p][aoff];        // hA(t-1)
            us8 a1u = *(const us8*)&hbufA[p][aoff + 32];
            us8 b0u = *(const us8*)&hbufB[p][aoff];        // hB(t-2)
            us8 b1u = *(const us8*)&hbufB[p][aoff + 32];
            bf16x8 a0 = __builtin_bit_cast(bf16x8, a0u);
            bf16x8 a1 = __builtin_bit_cast(bf16x8, a1u);
            bf16x8 b0 = __builtin_bit_cast(bf16x8, b0u);
            bf16x8 b1 = __builtin_bit_cast(bf16x8, b1u);
            f32x4 aR  = {br, br, br, br};
            f32x4 aZ  = {bz, bz, bz, bz};
            f32x4 aXn = {bnx, bnx, bnx, bnx};
            f32x4 aHn = {bnh, bnh, bnh, bnh};
            aR  = mfma16(a0, wA[0][0], aR);  aR  = mfma16(a1, wA[0][1], aR);
            aR  = mfma16(b0, wB[0][0], aR);  aR  = mfma16(b1, wB[0][1], aR);
            aZ  = mfma16(a0, wA[1][0], aZ);  aZ  = mfma16(a1, wA[1][1], aZ);
            aZ  = mfma16(b0, wB[1][0], aZ);  aZ  = mfma16(b1, wB[1][1], aZ);
            aXn = mfma16(a0, wA[2][0], aXn); aXn = mfma16(a1, wA[2][1], aXn);
            aHn = mfma16(b0, wB[2][0], aHn); aHn = mfma16(b1, wB[2][1], aHn);
            float gR = redist4(aR, c, q);
            float gZ = redist4(aZ, c, q);
            float gX = redist4(aXn, c, q);
            float gN = redist4(aHn, c, q);
            float rg = sigm(gR);
            float zg = sigm(gZ);
            float ng = tanh_f(gX + rg * gN);
            hreg = ng + zg * (hreg - ng);
            hbufB[p ^ 1][q * STR + ih] = f2bf(hreg);
        }
        __syncthreads();
    }

    // Epilogue: L1 computes the final step hB(511) from hA(511), hB(510)
    // (both in buffer 0 after 512 iterations).
    if (isL1){
        us8 a0u = *(const us8*)&hbufA[0][aoff];
        us8 a1u = *(const us8*)&hbufA[0][aoff + 32];
        us8 b0u = *(const us8*)&hbufB[0][aoff];
        us8 b1u = *(const us8*)&hbufB[0][aoff + 32];
        bf16x8 a0 = __builtin_bit_cast(bf16x8, a0u);
        bf16x8 a1 = __builtin_bit_cast(bf16x8, a1u);
        bf16x8 b0 = __builtin_bit_cast(bf16x8, b0u);
        bf16x8 b1 = __builtin_bit_cast(bf16x8, b1u);
        f32x4 aR  = {br, br, br, br};
        f32x4 aZ  = {bz, bz, bz, bz};
        f32x4 aXn = {bnx, bnx, bnx, bnx};
        f32x4 aHn = {bnh, bnh, bnh, bnh};
        aR  = mfma16(a0, wA[0][0], aR);  aR  = mfma16(a1, wA[0][1], aR);
        aR  = mfma16(b0, wB[0][0], aR);  aR  = mfma16(b1, wB[0][1], aR);
        aZ  = mfma16(a0, wA[1][0], aZ);  aZ  = mfma16(a1, wA[1][1], aZ);
        aZ  = mfma16(b0, wB[1][0], aZ);  aZ  = mfma16(b1, wB[1][1], aZ);
        aXn = mfma16(a0, wA[2][0], aXn); aXn = mfma16(a1, wA[2][1], aXn);
        aHn = mfma16(b0, wB[2][0], aHn); aHn = mfma16(b1, wB[2][1], aHn);
        float gR = redist4(aR, c, q);
        float gZ = redist4(aZ, c, q);
        float gX = redist4(aXn, c, q);
        float gN = redist4(aHn, c, q);
        float rg = sigm(gR);
        float zg = sigm(gZ);
        float ng = tanh_f(gX + rg * gN);
        float hf = ng + zg * (hreg - ng);
        outb[q][ih] = hf;
    }
    __syncthreads();

    // FC: out[row] = sum_i Wfc[i]*h2[row][i] + bfc
    if (tid < ROWS){
        float s = ld_any(bfc, 0, f32);
        for (int i2 = 0; i2 < 64; ++i2) s = fmaf(ld_any(Wfc, i2, f32), outb[tid][i2], s);
        if (f32) ((float*)outv)[row0 + tid] = s;
        else     ((ushort_t*)outv)[row0 + tid] = f2bf(s);
    }
}

extern "C" void kernel_launch(void* const* d_in, const int* in_sizes, int n_in,
                              void* d_out, int out_size, void* d_ws, size_t ws_size,
                              hipStream_t stream)
{
    (void)in_sizes; (void)n_in; (void)d_ws; (void)ws_size;
    const int B = out_size;            // O = 1 -> out_size == batch
    const int nblk = B / ROWS;         // 2048/4 = 512 blocks (2 per CU)
    gru_fused<<<nblk, 512, 0, stream>>>(
        d_in[0],
        d_in[1], d_in[2], d_in[3], d_in[4],
        d_in[5], d_in[6], d_in[7], d_in[8],
        d_in[9], d_in[10],
        d_out);
}